// Round 12
// baseline (291.211 us; speedup 1.0000x reference)
//
#include <hip/hip_runtime.h>
#include <hip/hip_bf16.h>

typedef unsigned short u16;
typedef unsigned int u32;
typedef __bf16 bf16x8 __attribute__((ext_vector_type(8)));
typedef float float4_ __attribute__((ext_vector_type(4)));

#define B_ 2
#define S_ 2048
#define E_ 1024
#define H_ 16
#define DH_ 64
#define M_ (B_*S_)
#define E2_ (E_*E_)
#define SCALE_ 0.03125f
#define LOG2E_ 1.4426950408889634f

__device__ __forceinline__ u16 f2bf(float f) {
    unsigned int x = __float_as_uint(f);
    x += 0x7fffu + ((x >> 16) & 1u);   // RNE
    return (u16)(x >> 16);
}

template <typename T> struct raw8;
template <> struct raw8<float> { float4_ lo, hi; };
template <> struct raw8<u16>   { bf16x8 v; };

__device__ __forceinline__ raw8<float> ldr8(const float* p) {
    raw8<float> r; const float4_* q = (const float4_*)p; r.lo = q[0]; r.hi = q[1]; return r;
}
__device__ __forceinline__ raw8<u16> ldr8(const u16* p) {
    raw8<u16> r; r.v = *(const bf16x8*)p; return r;
}
__device__ __forceinline__ bf16x8 cvt8(const raw8<u16>& r) { return r.v; }
__device__ __forceinline__ bf16x8 cvt8(const raw8<float>& r) {
    union { bf16x8 v; __hip_bfloat162 h[4]; } u;
    u.h[0] = __float22bfloat162_rn(float2{r.lo[0], r.lo[1]});
    u.h[1] = __float22bfloat162_rn(float2{r.lo[2], r.lo[3]});
    u.h[2] = __float22bfloat162_rn(float2{r.hi[0], r.hi[1]});
    u.h[3] = __float22bfloat162_rn(float2{r.hi[2], r.hi[3]});
    return u.v;
}
__device__ __forceinline__ bf16x8 ld8(const u16* p) { return *(const bf16x8*)p; }

// async 16B global -> LDS (direct-to-shared DMA). LDS dest must be
// wave-uniform base + lane*16 -- our chunk maps guarantee that.
__device__ __forceinline__ void async16(u16* lds, const u16* g) {
    __builtin_amdgcn_global_load_lds(
        (const __attribute__((address_space(1))) u32*)g,
        (__attribute__((address_space(3))) u32*)lds, 16, 0, 0);
}

// XOR chunk swizzle for [rows][32] bf16 tiles (64B rows, 4x 16B chunks).
__device__ __forceinline__ int swz32(int row, int col) {
    return row * 32 + ((((col >> 3) ^ (row & 3)) << 3) | (col & 7));
}

// ---- weight f32 -> bf16 conversion pass (Wq,Wk,Wv,Wo) ----
__global__ __launch_bounds__(256)
void convw_kernel(const float* __restrict__ Wq, const float* __restrict__ Wk,
                  const float* __restrict__ Wv, const float* __restrict__ Wo,
                  u16* __restrict__ Wqb, u16* __restrict__ Wkb,
                  u16* __restrict__ Wvb, u16* __restrict__ Wob) {
    const int which = blockIdx.y;
    const float* src = which == 0 ? Wq : which == 1 ? Wk : which == 2 ? Wv : Wo;
    u16* dst        = which == 0 ? Wqb : which == 1 ? Wkb : which == 2 ? Wvb : Wob;
    size_t off = ((size_t)blockIdx.x * 256 + threadIdx.x) * 8;
    *(bf16x8*)&dst[off] = cvt8(ldr8(&src[off]));
}

// ---- activation f32 -> bf16 conversion pass (q,k,v) ----
__global__ __launch_bounds__(256)
void convx_kernel(const float* __restrict__ q, const float* __restrict__ k,
                  const float* __restrict__ v,
                  u16* __restrict__ Xq, u16* __restrict__ Xk, u16* __restrict__ Xv) {
    const int which = blockIdx.y;
    const float* src = which == 0 ? q : which == 1 ? k : v;
    u16* dst        = which == 0 ? Xq : which == 1 ? Xk : Xv;
    size_t off = ((size_t)blockIdx.x * 256 + threadIdx.x) * 8;
    *(bf16x8*)&dst[off] = cvt8(ldr8(&src[off]));
}

// ---- projections: C = cscale * X(bf16)[M,1024] * Wb(bf16)[1024,1024]^T ----
// m97 structure: BOTH operands via global_load_lds, double-buffered,
// one barrier per K-step.
__global__ __launch_bounds__(256)
void proj_kernel(const u16* __restrict__ Xq, const u16* __restrict__ Xk, const u16* __restrict__ Xv,
                 const u16* __restrict__ Wqb, const u16* __restrict__ Wkb, const u16* __restrict__ Wvb,
                 u16* __restrict__ Qh, u16* __restrict__ Kh, u16* __restrict__ Vt) {
    const int z = blockIdx.z;
    const u16* A   = (z == 0) ? Xq : (z == 1) ? Xk : Xv;
    const u16* Wb  = (z == 0) ? Wqb : (z == 1) ? Wkb : Wvb;
    u16* C         = (z == 0) ? Qh : (z == 1) ? Kh : Vt;
    const float cscale = (z == 0) ? SCALE_ : 1.0f;   // fold softmax scale into Q
    const int transV = (z == 2);
    const int bm = blockIdx.x * 128, bn = blockIdx.y * 128;

    __shared__ u16 As[2][128 * 32];
    __shared__ u16 Bs[2][128 * 32];

    const int tid  = threadIdx.x;
    const int lane = tid & 63;
    const int w    = tid >> 6;
    const int wr   = (w >> 1) * 64, wc = (w & 1) * 64;
    const int m16  = lane & 15, quad = lane >> 4, q4 = quad * 4;

    const int row0 = tid >> 2, ch = tid & 3, row1 = row0 + 64;
    const int csw  = ((ch ^ (row0 & 3)) * 8);        // row1 has same (r&3)
    const u16* ag0 = &A[(size_t)(bm + row0) * 1024 + csw];
    const u16* ag1 = &A[(size_t)(bm + row1) * 1024 + csw];
    const u16* wg0 = &Wb[(size_t)(bn + row0) * 1024 + csw];
    const u16* wg1 = &Wb[(size_t)(bn + row1) * 1024 + csw];

    float4_ acc[4][4];
#pragma unroll
    for (int i = 0; i < 4; i++)
#pragma unroll
        for (int j = 0; j < 4; j++) acc[i][j] = (float4_){0.f, 0.f, 0.f, 0.f};

    async16((u16*)((char*)As[0] + (size_t)tid * 16), ag0);
    async16((u16*)((char*)As[0] + (size_t)tid * 16 + 4096), ag1);
    async16((u16*)((char*)Bs[0] + (size_t)tid * 16), wg0);
    async16((u16*)((char*)Bs[0] + (size_t)tid * 16 + 4096), wg1);
    __syncthreads();

    auto step = [&](int t, const u16* Asc, const u16* Bsc, u16* Asn, u16* Bsn) {
        if (t < 31) {
            const size_t ko = (size_t)(t + 1) * 32;
            async16((u16*)((char*)Asn + (size_t)tid * 16), ag0 + ko);
            async16((u16*)((char*)Asn + (size_t)tid * 16 + 4096), ag1 + ko);
            async16((u16*)((char*)Bsn + (size_t)tid * 16), wg0 + ko);
            async16((u16*)((char*)Bsn + (size_t)tid * 16 + 4096), wg1 + ko);
        }
        __builtin_amdgcn_sched_barrier(0);   // keep stage issue ahead of compute
        bf16x8 af[4], bfr[4];
#pragma unroll
        for (int rt = 0; rt < 4; rt++)
            af[rt] = *(const bf16x8*)&Asc[swz32(wr + rt * 16 + m16, quad * 8)];
#pragma unroll
        for (int ct = 0; ct < 4; ct++)
            bfr[ct] = *(const bf16x8*)&Bsc[swz32(wc + ct * 16 + m16, quad * 8)];
#pragma unroll
        for (int rt = 0; rt < 4; rt++)
#pragma unroll
            for (int ct = 0; ct < 4; ct++)
                acc[rt][ct] = __builtin_amdgcn_mfma_f32_16x16x32_bf16(af[rt], bfr[ct], acc[rt][ct], 0, 0, 0);
        if (t < 31) __syncthreads();
    };

    for (int t = 0; t < 32; t += 2) {
        step(t,     As[0], Bs[0], As[1], Bs[1]);
        step(t + 1, As[1], Bs[1], As[0], Bs[0]);
    }

#pragma unroll
    for (int rt = 0; rt < 4; rt++)
#pragma unroll
        for (int ct = 0; ct < 4; ct++)
#pragma unroll
            for (int r = 0; r < 4; r++) {
                int row = bm + wr + rt * 16 + q4 + r;
                int col = bn + wc + ct * 16 + m16;
                u16 val = f2bf(acc[rt][ct][r] * cscale);
                if (!transV) {
                    C[(size_t)row * 1024 + col] = val;
                } else {
                    int bb = row >> 11, s = row & 2047;
                    C[((size_t)(bb * 1024 + col)) * 2048 + s] = val;
                }
            }
}

// ---- output GEMM: C(f32)[M,1024] = AO(bf16) * Wob(bf16)^T, 128x64 tile ----
__global__ __launch_bounds__(256)
void out_kernel(const u16* __restrict__ AO, const u16* __restrict__ Wob, float* __restrict__ C) {
    const int bm = blockIdx.x * 128, bn = blockIdx.y * 64;

    __shared__ u16 As[2][128 * 32];
    __shared__ u16 Bs[2][64 * 32];

    const int tid  = threadIdx.x;
    const int lane = tid & 63;
    const int w    = tid >> 6;
    const int m16  = lane & 15, quad = lane >> 4, q4 = quad * 4;
    const int c1   = tid + 256;

    const int swc = (((tid & 3) ^ ((tid >> 2) & 3)) * 8);
    const u16* ag0 = &AO[(size_t)(bm + (tid >> 2)) * 1024 + swc];
    const u16* ag1 = &AO[(size_t)(bm + (c1 >> 2)) * 1024 + swc];
    const u16* bg  = &Wob[(size_t)(bn + (tid >> 2)) * 1024 + swc];

    float4_ acc[2][4];
#pragma unroll
    for (int i = 0; i < 2; i++)
#pragma unroll
        for (int j = 0; j < 4; j++) acc[i][j] = (float4_){0.f, 0.f, 0.f, 0.f};

    async16((u16*)((char*)As[0] + (size_t)tid * 16), ag0);
    async16((u16*)((char*)As[0] + (size_t)c1 * 16), ag1);
    async16((u16*)((char*)Bs[0] + (size_t)tid * 16), bg);
    __syncthreads();

    auto step = [&](int t, const u16* Asc, const u16* Bsc, u16* Asn, u16* Bsn) {
        if (t < 31) {
            async16((u16*)((char*)Asn + (size_t)tid * 16), ag0 + (t + 1) * 32);
            async16((u16*)((char*)Asn + (size_t)c1 * 16), ag1 + (t + 1) * 32);
            async16((u16*)((char*)Bsn + (size_t)tid * 16), bg + (t + 1) * 32);
        }
        __builtin_amdgcn_sched_barrier(0);
        bf16x8 af[2], bfr[4];
#pragma unroll
        for (int rt = 0; rt < 2; rt++)
            af[rt] = *(const bf16x8*)&Asc[swz32(w * 32 + rt * 16 + m16, quad * 8)];
#pragma unroll
        for (int ct = 0; ct < 4; ct++)
            bfr[ct] = *(const bf16x8*)&Bsc[swz32(ct * 16 + m16, quad * 8)];
#pragma unroll
        for (int rt = 0; rt < 2; rt++)
#pragma unroll
            for (int ct = 0; ct < 4; ct++)
                acc[rt][ct] = __builtin_amdgcn_mfma_f32_16x16x32_bf16(af[rt], bfr[ct], acc[rt][ct], 0, 0, 0);
        if (t < 31) __syncthreads();
    };

    for (int t = 0; t < 32; t += 2) {
        step(t,     As[0], Bs[0], As[1], Bs[1]);
        step(t + 1, As[1], Bs[1], As[0], Bs[0]);
    }

#pragma unroll
    for (int rt = 0; rt < 2; rt++)
#pragma unroll
        for (int ct = 0; ct < 4; ct++)
#pragma unroll
            for (int r = 0; r < 4; r++) {
                int row = bm + w * 32 + rt * 16 + q4 + r;
                int col = bn + ct * 16 + m16;
                C[(size_t)row * 1024 + col] = acc[rt][ct][r];
            }
}

// XOR swizzle for 64-col bf16 LDS tiles.
__device__ __forceinline__ int sw64(int row, int col) {
    return row * 64 + ((((col >> 3) ^ (row & 7)) << 3) | (col & 7));
}

// Flash attention, NO K/V STAGING: K/V is L2-resident (512 KB per (h,b);
// 2 MB/XCD working set < 4 MB L2), so each wave loads its MFMA fragments
// DIRECTLY from global into registers (16B/lane, full 64B lines). Deletes
// async16 staging, all in-loop barriers (P round-trip is wave-private:
// rows [w*16,w*16+16)), and 48 KB LDS. Waves fully independent; K issued
// before V so counted vmcnt leaves V in flight under QK+softmax.
// Plain launch_bounds(256): let the allocator pick ~120-140 VGPR rather
// than forcing an occupancy target that could trigger round-6-style
// spill heuristics. grid (16=h, 32=tq, 2=b), tq=31-y longest-first.
__global__ __launch_bounds__(256)
void attn_kernel(const u16* __restrict__ Qh, const u16* __restrict__ Kh,
                 const u16* __restrict__ Vt, u16* __restrict__ O) {
    const int h    = blockIdx.x;
    const int tq   = 31 - blockIdx.y;   // longest first
    const int b    = blockIdx.z;
    const int tid  = threadIdx.x;
    const int lane = tid & 63;
    const int w    = tid >> 6;          // 0..3
    const int m16  = lane & 15;
    const int quad = lane >> 4;
    const int q4   = quad * 4;

    __shared__ u16 Ps[64 * 64];         // 8 KB; wave-private row slices

    const size_t kbase = ((size_t)(b * S_)) * E_ + h * DH_;
    const size_t vbase = ((size_t)(b * 1024 + h * DH_)) * 2048;
    // lane-constant fragment offsets
    const u16* kl = Kh + kbase + (size_t)m16 * E_ + quad * 8;     // + (kt*64+ct*16)*E + ks*32
    const u16* vl = Vt + vbase + (size_t)m16 * 2048 + quad * 8;   // + dt*16*2048 + kt*64 + ks*32

    bf16x8 qf[2];
    {
        const u16* qa = Qh + ((size_t)(b * S_ + tq * 64 + w * 16 + m16)) * E_ + h * DH_;
        qf[0] = ld8(qa + quad * 8);
        qf[1] = ld8(qa + 32 + quad * 8);
    }

    float l_part[4] = {0.f, 0.f, 0.f, 0.f};
    float4_ o_acc[4];
#pragma unroll
    for (int dt = 0; dt < 4; dt++) o_acc[dt] = (float4_){0.f, 0.f, 0.f, 0.f};

    for (int t = 0; t <= tq; t++) {
        const u16* kt_base = kl + (size_t)t * 64 * E_;
        const u16* vt_base = vl + t * 64;

        // issue K first, then V: counted vmcnt lets QK start once K lands
        // while V (newest) stays in flight until PV (~600 cyc of cover).
        bf16x8 kf[4][2], vf[4][2];
#pragma unroll
        for (int ct = 0; ct < 4; ct++)
#pragma unroll
            for (int ks = 0; ks < 2; ks++)
                kf[ct][ks] = ld8(kt_base + (size_t)(ct * 16) * E_ + ks * 32);
#pragma unroll
        for (int dt = 0; dt < 4; dt++)
#pragma unroll
            for (int ks = 0; ks < 2; ks++)
                vf[dt][ks] = ld8(vt_base + (size_t)(dt * 16) * 2048 + ks * 32);

        float4_ sc[4];
#pragma unroll
        for (int ct = 0; ct < 4; ct++) sc[ct] = (float4_){0.f, 0.f, 0.f, 0.f};
#pragma unroll
        for (int ks = 0; ks < 2; ks++)
#pragma unroll
            for (int ct = 0; ct < 4; ct++)
                sc[ct] = __builtin_amdgcn_mfma_f32_16x16x32_bf16(qf[ks], kf[ct][ks], sc[ct], 0, 0, 0);

        // softmax numerator; bf16 via hardware v_cvt_pk (pairs along r)
#pragma unroll
        for (int ct = 0; ct < 4; ct++) {
            float pp[4];
            if (t != tq) {
#pragma unroll
                for (int r = 0; r < 4; r++) {
                    pp[r] = exp2f(sc[ct][r] * LOG2E_);
                    l_part[r] += pp[r];
                }
            } else {                    // diagonal tile: strict causal + (0,0)
#pragma unroll
                for (int r = 0; r < 4; r++) {
                    int i_loc = w * 16 + q4 + r;
                    int j_loc = ct * 16 + m16;
                    bool allow = (j_loc < i_loc) || (tq == 0 && i_loc == 0 && j_loc == 0);
                    pp[r] = allow ? exp2f(sc[ct][r] * LOG2E_) : 0.f;
                    l_part[r] += pp[r];
                }
            }
            union { __hip_bfloat162 h2; u16 s[2]; } u01, u23;
            u01.h2 = __float22bfloat162_rn(float2{pp[0], pp[1]});
            u23.h2 = __float22bfloat162_rn(float2{pp[2], pp[3]});
            Ps[sw64(w * 16 + q4 + 0, ct * 16 + m16)] = u01.s[0];
            Ps[sw64(w * 16 + q4 + 1, ct * 16 + m16)] = u01.s[1];
            Ps[sw64(w * 16 + q4 + 2, ct * 16 + m16)] = u23.s[0];
            Ps[sw64(w * 16 + q4 + 3, ct * 16 + m16)] = u23.s[1];
        }

#pragma unroll
        for (int ks = 0; ks < 2; ks++) {
            bf16x8 pf = *(const bf16x8*)&Ps[sw64(w * 16 + m16, ks * 32 + quad * 8)];
#pragma unroll
            for (int dt = 0; dt < 4; dt++)
                o_acc[dt] = __builtin_amdgcn_mfma_f32_16x16x32_bf16(pf, vf[dt][ks], o_acc[dt], 0, 0, 0);
        }
    }

    const size_t obase = ((size_t)(b * S_ + tq * 64)) * E_ + h * DH_;
#pragma unroll
    for (int r = 0; r < 4; r++) {
        float l = l_part[r];
#pragma unroll
        for (int msk = 1; msk <= 8; msk <<= 1) l += __shfl_xor(l, msk);
        float inv_l = 1.0f / l;
        int row = w * 16 + q4 + r;
#pragma unroll
        for (int dt = 0; dt < 4; dt++) {
            int col = dt * 16 + m16;
            O[obase + (size_t)row * E_ + col] = f2bf(o_acc[dt][r] * inv_l);
        }
    }
}

extern "C" void kernel_launch(void* const* d_in, const int* in_sizes, int n_in,
                              void* d_out, int out_size, void* d_ws, size_t ws_size,
                              hipStream_t stream) {
    const float* q  = (const float*)d_in[0];
    const float* k  = (const float*)d_in[1];
    const float* v  = (const float*)d_in[2];
    const float* Wq = (const float*)d_in[3];
    const float* Wk = (const float*)d_in[4];
    const float* Wv = (const float*)d_in[5];
    const float* Wo = (const float*)d_in[6];

    const size_t ME = (size_t)M_ * E_;
    u16* ws  = (u16*)d_ws;
    u16* Qh  = ws;                      // [M,E] bf16, Q pre-scaled by SCALE_
    u16* Kh  = ws + ME;
    u16* Vt  = ws + 2 * ME;             // [B][1024][2048] bf16 V^T
    u16* AO  = ws + 3 * ME;             // attn out; first 3*E2 aliased as W bufs
    u16* Wqb = AO;                      // dead before attn writes AO
    u16* Wkb = AO + E2_;
    u16* Wvb = AO + 2 * (size_t)E2_;
    u16* Wob = ws + 4 * ME;             // +2 MB
    u16* Xv  = ws + 4 * ME + E2_;       // +8 MB
    u16* Xq  = (u16*)d_out;             // d_out (16.8 MB f32) is dead until
    u16* Xk  = Xq + ME;                 // out_kernel: stash Xq,Xk there (exact fit)

    dim3 blk(256);
    convw_kernel<<<dim3(512, 4), blk, 0, stream>>>(Wq, Wk, Wv, Wo, Wqb, Wkb, Wvb, Wob);
    convx_kernel<<<dim3(2048, 3), blk, 0, stream>>>(q, k, v, Xq, Xk, Xv);
    proj_kernel<<<dim3(32, 8, 3), blk, 0, stream>>>(Xq, Xk, Xv, Wqb, Wkb, Wvb, Qh, Kh, Vt);
    attn_kernel<<<dim3(16, 32, 2), blk, 0, stream>>>(Qh, Kh, Vt, AO);
    out_kernel<<<dim3(32, 16), blk, 0, stream>>>(AO, Wob, (float*)d_out);
}

// Round 13
// 213.537 us; speedup vs baseline: 1.3637x; 1.3637x over previous
//
#include <hip/hip_runtime.h>
#include <hip/hip_bf16.h>

typedef unsigned short u16;
typedef unsigned int u32;
typedef __bf16 bf16x8 __attribute__((ext_vector_type(8)));
typedef float float4_ __attribute__((ext_vector_type(4)));

#define B_ 2
#define S_ 2048
#define E_ 1024
#define H_ 16
#define DH_ 64
#define M_ (B_*S_)
#define E2_ (E_*E_)
#define SCALE_ 0.03125f
#define LOG2E_ 1.4426950408889634f

__device__ __forceinline__ u16 f2bf(float f) {
    unsigned int x = __float_as_uint(f);
    x += 0x7fffu + ((x >> 16) & 1u);   // RNE
    return (u16)(x >> 16);
}

template <typename T> struct raw8;
template <> struct raw8<float> { float4_ lo, hi; };
template <> struct raw8<u16>   { bf16x8 v; };

__device__ __forceinline__ raw8<float> ldr8(const float* p) {
    raw8<float> r; const float4_* q = (const float4_*)p; r.lo = q[0]; r.hi = q[1]; return r;
}
__device__ __forceinline__ raw8<u16> ldr8(const u16* p) {
    raw8<u16> r; r.v = *(const bf16x8*)p; return r;
}
__device__ __forceinline__ bf16x8 cvt8(const raw8<u16>& r) { return r.v; }
__device__ __forceinline__ bf16x8 cvt8(const raw8<float>& r) {
    union { bf16x8 v; __hip_bfloat162 h[4]; } u;
    u.h[0] = __float22bfloat162_rn(float2{r.lo[0], r.lo[1]});
    u.h[1] = __float22bfloat162_rn(float2{r.lo[2], r.lo[3]});
    u.h[2] = __float22bfloat162_rn(float2{r.hi[0], r.hi[1]});
    u.h[3] = __float22bfloat162_rn(float2{r.hi[2], r.hi[3]});
    return u.v;
}
__device__ __forceinline__ bf16x8 ld8(const u16* p) { return *(const bf16x8*)p; }

// async 16B global -> LDS (direct-to-shared DMA). LDS dest must be
// wave-uniform base + lane*16 -- our chunk maps guarantee that.
__device__ __forceinline__ void async16(u16* lds, const u16* g) {
    __builtin_amdgcn_global_load_lds(
        (const __attribute__((address_space(1))) u32*)g,
        (__attribute__((address_space(3))) u32*)lds, 16, 0, 0);
}

// XOR chunk swizzle for [rows][32] bf16 tiles (64B rows, 4x 16B chunks).
__device__ __forceinline__ int swz32(int row, int col) {
    return row * 32 + ((((col >> 3) ^ (row & 3)) << 3) | (col & 7));
}

// ---- fused f32 -> bf16 conversion (q,k,v,Wq,Wk,Wv,Wo in ONE launch) ----
// blocks 0..6143: X slices (2048 each); 6144..8191: W slices (512 each).
__global__ __launch_bounds__(256)
void conv_all_kernel(const float* __restrict__ q, const float* __restrict__ k,
                     const float* __restrict__ v,
                     const float* __restrict__ Wq, const float* __restrict__ Wk,
                     const float* __restrict__ Wv, const float* __restrict__ Wo,
                     u16* __restrict__ Xq, u16* __restrict__ Xk, u16* __restrict__ Xv,
                     u16* __restrict__ Wqb, u16* __restrict__ Wkb,
                     u16* __restrict__ Wvb, u16* __restrict__ Wob) {
    const int bid = blockIdx.x;
    const float* src;
    u16* dst;
    size_t base;
    if (bid < 6144) {
        const int which = bid >> 11, off = bid & 2047;
        src = which == 0 ? q : which == 1 ? k : v;
        dst = which == 0 ? Xq : which == 1 ? Xk : Xv;
        base = (size_t)off * 2048;
    } else {
        const int wb = bid - 6144;
        const int which = wb >> 9, off = wb & 511;
        src = which == 0 ? Wq : which == 1 ? Wk : which == 2 ? Wv : Wo;
        dst = which == 0 ? Wqb : which == 1 ? Wkb : which == 2 ? Wvb : Wob;
        base = (size_t)off * 2048;
    }
    const size_t i = base + (size_t)threadIdx.x * 8;
    *(bf16x8*)&dst[i] = cvt8(ldr8(&src[i]));
}

// ---- projections: C = cscale * X(bf16)[M,1024] * Wb(bf16)[1024,1024]^T ----
// m97 structure: BOTH operands via global_load_lds, double-buffered,
// one barrier per K-step.
__global__ __launch_bounds__(256)
void proj_kernel(const u16* __restrict__ Xq, const u16* __restrict__ Xk, const u16* __restrict__ Xv,
                 const u16* __restrict__ Wqb, const u16* __restrict__ Wkb, const u16* __restrict__ Wvb,
                 u16* __restrict__ Qh, u16* __restrict__ Kh, u16* __restrict__ Vt) {
    const int z = blockIdx.z;
    const u16* A   = (z == 0) ? Xq : (z == 1) ? Xk : Xv;
    const u16* Wb  = (z == 0) ? Wqb : (z == 1) ? Wkb : Wvb;
    u16* C         = (z == 0) ? Qh : (z == 1) ? Kh : Vt;
    const float cscale = (z == 0) ? SCALE_ : 1.0f;   // fold softmax scale into Q
    const int transV = (z == 2);
    const int bm = blockIdx.x * 128, bn = blockIdx.y * 128;

    __shared__ u16 As[2][128 * 32];
    __shared__ u16 Bs[2][128 * 32];

    const int tid  = threadIdx.x;
    const int lane = tid & 63;
    const int w    = tid >> 6;
    const int wr   = (w >> 1) * 64, wc = (w & 1) * 64;
    const int m16  = lane & 15, quad = lane >> 4, q4 = quad * 4;

    const int row0 = tid >> 2, ch = tid & 3, row1 = row0 + 64;
    const int csw  = ((ch ^ (row0 & 3)) * 8);        // row1 has same (r&3)
    const u16* ag0 = &A[(size_t)(bm + row0) * 1024 + csw];
    const u16* ag1 = &A[(size_t)(bm + row1) * 1024 + csw];
    const u16* wg0 = &Wb[(size_t)(bn + row0) * 1024 + csw];
    const u16* wg1 = &Wb[(size_t)(bn + row1) * 1024 + csw];

    float4_ acc[4][4];
#pragma unroll
    for (int i = 0; i < 4; i++)
#pragma unroll
        for (int j = 0; j < 4; j++) acc[i][j] = (float4_){0.f, 0.f, 0.f, 0.f};

    async16((u16*)((char*)As[0] + (size_t)tid * 16), ag0);
    async16((u16*)((char*)As[0] + (size_t)tid * 16 + 4096), ag1);
    async16((u16*)((char*)Bs[0] + (size_t)tid * 16), wg0);
    async16((u16*)((char*)Bs[0] + (size_t)tid * 16 + 4096), wg1);
    __syncthreads();

    auto step = [&](int t, const u16* Asc, const u16* Bsc, u16* Asn, u16* Bsn) {
        if (t < 31) {
            const size_t ko = (size_t)(t + 1) * 32;
            async16((u16*)((char*)Asn + (size_t)tid * 16), ag0 + ko);
            async16((u16*)((char*)Asn + (size_t)tid * 16 + 4096), ag1 + ko);
            async16((u16*)((char*)Bsn + (size_t)tid * 16), wg0 + ko);
            async16((u16*)((char*)Bsn + (size_t)tid * 16 + 4096), wg1 + ko);
        }
        __builtin_amdgcn_sched_barrier(0);   // keep stage issue ahead of compute
        bf16x8 af[4], bfr[4];
#pragma unroll
        for (int rt = 0; rt < 4; rt++)
            af[rt] = *(const bf16x8*)&Asc[swz32(wr + rt * 16 + m16, quad * 8)];
#pragma unroll
        for (int ct = 0; ct < 4; ct++)
            bfr[ct] = *(const bf16x8*)&Bsc[swz32(wc + ct * 16 + m16, quad * 8)];
#pragma unroll
        for (int rt = 0; rt < 4; rt++)
#pragma unroll
            for (int ct = 0; ct < 4; ct++)
                acc[rt][ct] = __builtin_amdgcn_mfma_f32_16x16x32_bf16(af[rt], bfr[ct], acc[rt][ct], 0, 0, 0);
        if (t < 31) __syncthreads();
    };

    for (int t = 0; t < 32; t += 2) {
        step(t,     As[0], Bs[0], As[1], Bs[1]);
        step(t + 1, As[1], Bs[1], As[0], Bs[0]);
    }

#pragma unroll
    for (int rt = 0; rt < 4; rt++)
#pragma unroll
        for (int ct = 0; ct < 4; ct++)
#pragma unroll
            for (int r = 0; r < 4; r++) {
                int row = bm + wr + rt * 16 + q4 + r;
                int col = bn + wc + ct * 16 + m16;
                u16 val = f2bf(acc[rt][ct][r] * cscale);
                if (!transV) {
                    C[(size_t)row * 1024 + col] = val;
                } else {
                    int bb = row >> 11, s = row & 2047;
                    C[((size_t)(bb * 1024 + col)) * 2048 + s] = val;
                }
            }
}

// ---- output GEMM: C(f32)[M,1024] = AO(bf16) * Wob(bf16)^T, 128x64 tile ----
__global__ __launch_bounds__(256)
void out_kernel(const u16* __restrict__ AO, const u16* __restrict__ Wob, float* __restrict__ C) {
    const int bm = blockIdx.x * 128, bn = blockIdx.y * 64;

    __shared__ u16 As[2][128 * 32];
    __shared__ u16 Bs[2][64 * 32];

    const int tid  = threadIdx.x;
    const int lane = tid & 63;
    const int w    = tid >> 6;
    const int m16  = lane & 15, quad = lane >> 4, q4 = quad * 4;
    const int c1   = tid + 256;

    const int swc = (((tid & 3) ^ ((tid >> 2) & 3)) * 8);
    const u16* ag0 = &AO[(size_t)(bm + (tid >> 2)) * 1024 + swc];
    const u16* ag1 = &AO[(size_t)(bm + (c1 >> 2)) * 1024 + swc];
    const u16* bg  = &Wob[(size_t)(bn + (tid >> 2)) * 1024 + swc];

    float4_ acc[2][4];
#pragma unroll
    for (int i = 0; i < 2; i++)
#pragma unroll
        for (int j = 0; j < 4; j++) acc[i][j] = (float4_){0.f, 0.f, 0.f, 0.f};

    async16((u16*)((char*)As[0] + (size_t)tid * 16), ag0);
    async16((u16*)((char*)As[0] + (size_t)c1 * 16), ag1);
    async16((u16*)((char*)Bs[0] + (size_t)tid * 16), bg);
    __syncthreads();

    auto step = [&](int t, const u16* Asc, const u16* Bsc, u16* Asn, u16* Bsn) {
        if (t < 31) {
            async16((u16*)((char*)Asn + (size_t)tid * 16), ag0 + (t + 1) * 32);
            async16((u16*)((char*)Asn + (size_t)c1 * 16), ag1 + (t + 1) * 32);
            async16((u16*)((char*)Bsn + (size_t)tid * 16), bg + (t + 1) * 32);
        }
        __builtin_amdgcn_sched_barrier(0);
        bf16x8 af[2], bfr[4];
#pragma unroll
        for (int rt = 0; rt < 2; rt++)
            af[rt] = *(const bf16x8*)&Asc[swz32(w * 32 + rt * 16 + m16, quad * 8)];
#pragma unroll
        for (int ct = 0; ct < 4; ct++)
            bfr[ct] = *(const bf16x8*)&Bsc[swz32(ct * 16 + m16, quad * 8)];
#pragma unroll
        for (int rt = 0; rt < 2; rt++)
#pragma unroll
            for (int ct = 0; ct < 4; ct++)
                acc[rt][ct] = __builtin_amdgcn_mfma_f32_16x16x32_bf16(af[rt], bfr[ct], acc[rt][ct], 0, 0, 0);
        if (t < 31) __syncthreads();
    };

    for (int t = 0; t < 32; t += 2) {
        step(t,     As[0], Bs[0], As[1], Bs[1]);
        step(t + 1, As[1], Bs[1], As[0], Bs[0]);
    }

#pragma unroll
    for (int rt = 0; rt < 2; rt++)
#pragma unroll
        for (int ct = 0; ct < 4; ct++)
#pragma unroll
            for (int r = 0; r < 4; r++) {
                int row = bm + w * 32 + rt * 16 + q4 + r;
                int col = bn + ct * 16 + m16;
                C[(size_t)row * 1024 + col] = acc[rt][ct][r];
            }
}

// XOR swizzle for 64-col bf16 LDS tiles.
__device__ __forceinline__ int sw64(int row, int col) {
    return row * 64 + ((((col >> 3) ^ (row & 7)) << 3) | (col & 7));
}

// Flash attention: ONE q-tile per block, 256 threads (4 waves).
// T3/T4 pipeline: 3-buffer K/V ring, 2-deep prefetch, COUNTED
// s_waitcnt vmcnt(4) + raw s_barrier (never vmcnt(0) in-loop) so tile
// t+1's loads get two tile-times of latency cover and t+2's stay in
// flight across the barrier. (Round-12 A/B: direct-to-reg K/V without
// staging regressed 55->136 us -- allocator at 88 VGPR serialized the
// 16 loads/tile; LDS staging decouples load issue from reg liveness.)
// grid (16=h, 32=tq, 2=b), tq=31-blockIdx.y: longest blocks first.
__global__ __launch_bounds__(256, 2)
void attn_kernel(const u16* __restrict__ Qh, const u16* __restrict__ Kh,
                 const u16* __restrict__ Vt, u16* __restrict__ O) {
    const int h    = blockIdx.x;
    const int tq   = 31 - blockIdx.y;   // longest first
    const int b    = blockIdx.z;
    const int tid  = threadIdx.x;
    const int lane = tid & 63;
    const int w    = tid >> 6;          // 0..3
    const int m16  = lane & 15;
    const int quad = lane >> 4;
    const int q4   = quad * 4;

    __shared__ u16 Ks[3][64 * 64];      // 24 KB ring
    __shared__ u16 Vs[3][64 * 64];      // 24 KB ring
    __shared__ u16 Ps[64 * 64];         // 8 KB

    const int srow0 = tid >> 3;                        // 0..31
    const int ssw   = (((tid & 7) ^ (srow0 & 7)) * 8); // swizzled col (u16)

    const size_t kbase = ((size_t)(b * S_)) * E_ + h * DH_;
    const size_t vbase = ((size_t)(b * 1024 + h * DH_)) * 2048;
    const u16* kg0 = &Kh[kbase + (size_t)srow0 * E_ + ssw];    // + kt*64*E_
    const u16* kg1 = kg0 + (size_t)32 * E_;
    const u16* vg0 = &Vt[vbase + (size_t)srow0 * 2048 + ssw];  // + kt*64
    const u16* vg1 = vg0 + (size_t)32 * 2048;

    bf16x8 qf[2];
    {
        const u16* qa = Qh + ((size_t)(b * S_ + tq * 64 + w * 16 + m16)) * E_ + h * DH_;
        qf[0] = ld8(qa + quad * 8);
        qf[1] = ld8(qa + 32 + quad * 8);
    }

    float l_part[4] = {0.f, 0.f, 0.f, 0.f};
    float4_ o_acc[4];
#pragma unroll
    for (int dt = 0; dt < 4; dt++) o_acc[dt] = (float4_){0.f, 0.f, 0.f, 0.f};

    u16* k0 = &Ks[0][0]; u16* k1 = &Ks[1][0]; u16* k2 = &Ks[2][0];
    u16* v0 = &Vs[0][0]; u16* v1 = &Vs[1][0]; u16* v2 = &Vs[2][0];

    auto stage_to = [&](u16* kb, u16* vb, int tile) {   // 4 async16/thread
        const size_t ko = (size_t)tile * 64 * E_;
        const int    vo = tile * 64;
        async16(kb + tid * 8, kg0 + ko);
        async16(kb + (tid + 256) * 8, kg1 + ko);
        async16(vb + tid * 8, vg0 + vo);
        async16(vb + (tid + 256) * 8, vg1 + vo);
    };

    // prologue: tiles 0 -> buf0, min(1,tq) -> buf1; wait only tile 0 (oldest 4)
    stage_to(k0, v0, 0);
    stage_to(k1, v1, tq > 0 ? 1 : 0);
    asm volatile("s_waitcnt vmcnt(4)" ::: "memory");
    __builtin_amdgcn_s_barrier();
    __builtin_amdgcn_sched_barrier(0);

    for (int t = 0; t <= tq; t++) {
        // stage tile t+2 (clamped; duplicate-stage harmless, keeps vmcnt uniform)
        stage_to(k2, v2, (t + 2 <= tq) ? (t + 2) : tq);
        __builtin_amdgcn_sched_barrier(0);

        float4_ sc[4];
#pragma unroll
        for (int ct = 0; ct < 4; ct++) sc[ct] = (float4_){0.f, 0.f, 0.f, 0.f};
#pragma unroll
        for (int ks = 0; ks < 2; ks++)
#pragma unroll
            for (int ct = 0; ct < 4; ct++) {
                bf16x8 kf = *(const bf16x8*)&k0[sw64(ct * 16 + m16, ks * 32 + quad * 8)];
                sc[ct] = __builtin_amdgcn_mfma_f32_16x16x32_bf16(qf[ks], kf, sc[ct], 0, 0, 0);
            }

        // softmax numerator; bf16 via hardware v_cvt_pk (pairs along r)
#pragma unroll
        for (int ct = 0; ct < 4; ct++) {
            float pp[4];
            if (t != tq) {
#pragma unroll
                for (int r = 0; r < 4; r++) {
                    pp[r] = exp2f(sc[ct][r] * LOG2E_);
                    l_part[r] += pp[r];
                }
            } else {                    // diagonal tile: strict causal + (0,0)
#pragma unroll
                for (int r = 0; r < 4; r++) {
                    int i_loc = w * 16 + q4 + r;
                    int j_loc = ct * 16 + m16;
                    bool allow = (j_loc < i_loc) || (tq == 0 && i_loc == 0 && j_loc == 0);
                    pp[r] = allow ? exp2f(sc[ct][r] * LOG2E_) : 0.f;
                    l_part[r] += pp[r];
                }
            }
            union { __hip_bfloat162 h2; u16 s[2]; } u01, u23;
            u01.h2 = __float22bfloat162_rn(float2{pp[0], pp[1]});
            u23.h2 = __float22bfloat162_rn(float2{pp[2], pp[3]});
            Ps[sw64(w * 16 + q4 + 0, ct * 16 + m16)] = u01.s[0];
            Ps[sw64(w * 16 + q4 + 1, ct * 16 + m16)] = u01.s[1];
            Ps[sw64(w * 16 + q4 + 2, ct * 16 + m16)] = u23.s[0];
            Ps[sw64(w * 16 + q4 + 3, ct * 16 + m16)] = u23.s[1];
        }

#pragma unroll
        for (int ks = 0; ks < 2; ks++) {
            bf16x8 pf = *(const bf16x8*)&Ps[sw64(w * 16 + m16, ks * 32 + quad * 8)];
#pragma unroll
            for (int dt = 0; dt < 4; dt++) {
                bf16x8 vf = *(const bf16x8*)&v0[sw64(dt * 16 + m16, ks * 32 + quad * 8)];
                o_acc[dt] = __builtin_amdgcn_mfma_f32_16x16x32_bf16(pf, vf, o_acc[dt], 0, 0, 0);
            }
        }

        // counted wait: tile t+1's 4 loads done, tile t+2's 4 stay in flight
        asm volatile("s_waitcnt vmcnt(4)" ::: "memory");
        __builtin_amdgcn_s_barrier();
        __builtin_amdgcn_sched_barrier(0);

        u16* tk = k0; k0 = k1; k1 = k2; k2 = tk;
        u16* tv = v0; v0 = v1; v1 = v2; v2 = tv;
    }
    asm volatile("s_waitcnt vmcnt(0)" ::: "memory");   // drain DMA before exit

    const size_t obase = ((size_t)(b * S_ + tq * 64)) * E_ + h * DH_;
#pragma unroll
    for (int r = 0; r < 4; r++) {
        float l = l_part[r];
#pragma unroll
        for (int msk = 1; msk <= 8; msk <<= 1) l += __shfl_xor(l, msk);
        float inv_l = 1.0f / l;
        int row = w * 16 + q4 + r;
#pragma unroll
        for (int dt = 0; dt < 4; dt++) {
            int col = dt * 16 + m16;
            O[obase + (size_t)row * E_ + col] = f2bf(o_acc[dt][r] * inv_l);
        }
    }
}

extern "C" void kernel_launch(void* const* d_in, const int* in_sizes, int n_in,
                              void* d_out, int out_size, void* d_ws, size_t ws_size,
                              hipStream_t stream) {
    const float* q  = (const float*)d_in[0];
    const float* k  = (const float*)d_in[1];
    const float* v  = (const float*)d_in[2];
    const float* Wq = (const float*)d_in[3];
    const float* Wk = (const float*)d_in[4];
    const float* Wv = (const float*)d_in[5];
    const float* Wo = (const float*)d_in[6];

    const size_t ME = (size_t)M_ * E_;
    u16* ws  = (u16*)d_ws;
    u16* Qh  = ws;                      // [M,E] bf16, Q pre-scaled by SCALE_
    u16* Kh  = ws + ME;
    u16* Vt  = ws + 2 * ME;             // [B][1024][2048] bf16 V^T
    u16* AO  = ws + 3 * ME;             // attn out; first 3*E2 aliased as W bufs
    u16* Wqb = AO;                      // dead before attn writes AO
    u16* Wkb = AO + E2_;
    u16* Wvb = AO + 2 * (size_t)E2_;
    u16* Wob = ws + 4 * ME;             // +2 MB
    u16* Xv  = ws + 4 * ME + E2_;       // +8 MB
    u16* Xq  = (u16*)d_out;             // d_out (16.8 MB f32) is dead until
    u16* Xk  = Xq + ME;                 // out_kernel: stash Xq,Xk there (exact fit)

    dim3 blk(256);
    conv_all_kernel<<<dim3(8192), blk, 0, stream>>>(q, k, v, Wq, Wk, Wv, Wo,
                                                    Xq, Xk, Xv, Wqb, Wkb, Wvb, Wob);
    proj_kernel<<<dim3(32, 8, 3), blk, 0, stream>>>(Xq, Xk, Xv, Wqb, Wkb, Wvb, Qh, Kh, Vt);
    attn_kernel<<<dim3(16, 32, 2), blk, 0, stream>>>(Qh, Kh, Vt, AO);
    out_kernel<<<dim3(32, 16), blk, 0, stream>>>(AO, Wob, (float*)d_out);
}

// Round 15
// 212.486 us; speedup vs baseline: 1.3705x; 1.0049x over previous
//
#include <hip/hip_runtime.h>
#include <hip/hip_bf16.h>

typedef unsigned short u16;
typedef unsigned int u32;
typedef __bf16 bf16x8 __attribute__((ext_vector_type(8)));
typedef float float4_ __attribute__((ext_vector_type(4)));

#define B_ 2
#define S_ 2048
#define E_ 1024
#define H_ 16
#define DH_ 64
#define M_ (B_*S_)
#define E2_ (E_*E_)
#define SCALE_ 0.03125f
#define LOG2E_ 1.4426950408889634f

__device__ __forceinline__ u16 f2bf(float f) {
    unsigned int x = __float_as_uint(f);
    x += 0x7fffu + ((x >> 16) & 1u);   // RNE
    return (u16)(x >> 16);
}

template <typename T> struct raw8;
template <> struct raw8<float> { float4_ lo, hi; };
template <> struct raw8<u16>   { bf16x8 v; };

__device__ __forceinline__ raw8<float> ldr8(const float* p) {
    raw8<float> r; const float4_* q = (const float4_*)p; r.lo = q[0]; r.hi = q[1]; return r;
}
__device__ __forceinline__ raw8<u16> ldr8(const u16* p) {
    raw8<u16> r; r.v = *(const bf16x8*)p; return r;
}
__device__ __forceinline__ bf16x8 cvt8(const raw8<u16>& r) { return r.v; }
__device__ __forceinline__ bf16x8 cvt8(const raw8<float>& r) {
    union { bf16x8 v; __hip_bfloat162 h[4]; } u;
    u.h[0] = __float22bfloat162_rn(float2{r.lo[0], r.lo[1]});
    u.h[1] = __float22bfloat162_rn(float2{r.lo[2], r.lo[3]});
    u.h[2] = __float22bfloat162_rn(float2{r.hi[0], r.hi[1]});
    u.h[3] = __float22bfloat162_rn(float2{r.hi[2], r.hi[3]});
    return u.v;
}
__device__ __forceinline__ bf16x8 ld8(const u16* p) { return *(const bf16x8*)p; }

// async 16B global -> LDS (direct-to-shared DMA). LDS dest must be
// wave-uniform base + lane*16 -- our chunk maps guarantee that.
__device__ __forceinline__ void async16(u16* lds, const u16* g) {
    __builtin_amdgcn_global_load_lds(
        (const __attribute__((address_space(1))) u32*)g,
        (__attribute__((address_space(3))) u32*)lds, 16, 0, 0);
}

// XOR chunk swizzle for [rows][32] bf16 tiles (64B rows, 4x 16B chunks).
__device__ __forceinline__ int swz32(int row, int col) {
    return row * 32 + ((((col >> 3) ^ (row & 3)) << 3) | (col & 7));
}

// ---- fused f32 -> bf16 conversion (q,k,v,Wq,Wk,Wv,Wo in ONE launch) ----
// blocks 0..6143: X slices (2048 each); 6144..8191: W slices (512 each).
__global__ __launch_bounds__(256)
void conv_all_kernel(const float* __restrict__ q, const float* __restrict__ k,
                     const float* __restrict__ v,
                     const float* __restrict__ Wq, const float* __restrict__ Wk,
                     const float* __restrict__ Wv, const float* __restrict__ Wo,
                     u16* __restrict__ Xq, u16* __restrict__ Xk, u16* __restrict__ Xv,
                     u16* __restrict__ Wqb, u16* __restrict__ Wkb,
                     u16* __restrict__ Wvb, u16* __restrict__ Wob) {
    const int bid = blockIdx.x;
    const float* src;
    u16* dst;
    size_t base;
    if (bid < 6144) {
        const int which = bid >> 11, off = bid & 2047;
        src = which == 0 ? q : which == 1 ? k : v;
        dst = which == 0 ? Xq : which == 1 ? Xk : Xv;
        base = (size_t)off * 2048;
    } else {
        const int wb = bid - 6144;
        const int which = wb >> 9, off = wb & 511;
        src = which == 0 ? Wq : which == 1 ? Wk : which == 2 ? Wv : Wo;
        dst = which == 0 ? Wqb : which == 1 ? Wkb : which == 2 ? Wvb : Wob;
        base = (size_t)off * 2048;
    }
    const size_t i = base + (size_t)threadIdx.x * 8;
    *(bf16x8*)&dst[i] = cvt8(ldr8(&src[i]));
}

// ---- projections: C = cscale * X(bf16)[M,1024] * Wb(bf16)[1024,1024]^T ----
// m97 structure: BOTH operands via global_load_lds, double-buffered,
// one barrier per K-step.
__global__ __launch_bounds__(256)
void proj_kernel(const u16* __restrict__ Xq, const u16* __restrict__ Xk, const u16* __restrict__ Xv,
                 const u16* __restrict__ Wqb, const u16* __restrict__ Wkb, const u16* __restrict__ Wvb,
                 u16* __restrict__ Qh, u16* __restrict__ Kh, u16* __restrict__ Vt) {
    const int z = blockIdx.z;
    const u16* A   = (z == 0) ? Xq : (z == 1) ? Xk : Xv;
    const u16* Wb  = (z == 0) ? Wqb : (z == 1) ? Wkb : Wvb;
    u16* C         = (z == 0) ? Qh : (z == 1) ? Kh : Vt;
    const float cscale = (z == 0) ? SCALE_ : 1.0f;   // fold softmax scale into Q
    const int transV = (z == 2);
    const int bm = blockIdx.x * 128, bn = blockIdx.y * 128;

    __shared__ u16 As[2][128 * 32];
    __shared__ u16 Bs[2][128 * 32];

    const int tid  = threadIdx.x;
    const int lane = tid & 63;
    const int w    = tid >> 6;
    const int wr   = (w >> 1) * 64, wc = (w & 1) * 64;
    const int m16  = lane & 15, quad = lane >> 4, q4 = quad * 4;

    const int row0 = tid >> 2, ch = tid & 3, row1 = row0 + 64;
    const int csw  = ((ch ^ (row0 & 3)) * 8);        // row1 has same (r&3)
    const u16* ag0 = &A[(size_t)(bm + row0) * 1024 + csw];
    const u16* ag1 = &A[(size_t)(bm + row1) * 1024 + csw];
    const u16* wg0 = &Wb[(size_t)(bn + row0) * 1024 + csw];
    const u16* wg1 = &Wb[(size_t)(bn + row1) * 1024 + csw];

    float4_ acc[4][4];
#pragma unroll
    for (int i = 0; i < 4; i++)
#pragma unroll
        for (int j = 0; j < 4; j++) acc[i][j] = (float4_){0.f, 0.f, 0.f, 0.f};

    async16((u16*)((char*)As[0] + (size_t)tid * 16), ag0);
    async16((u16*)((char*)As[0] + (size_t)tid * 16 + 4096), ag1);
    async16((u16*)((char*)Bs[0] + (size_t)tid * 16), wg0);
    async16((u16*)((char*)Bs[0] + (size_t)tid * 16 + 4096), wg1);
    __syncthreads();

    auto step = [&](int t, const u16* Asc, const u16* Bsc, u16* Asn, u16* Bsn) {
        if (t < 31) {
            const size_t ko = (size_t)(t + 1) * 32;
            async16((u16*)((char*)Asn + (size_t)tid * 16), ag0 + ko);
            async16((u16*)((char*)Asn + (size_t)tid * 16 + 4096), ag1 + ko);
            async16((u16*)((char*)Bsn + (size_t)tid * 16), wg0 + ko);
            async16((u16*)((char*)Bsn + (size_t)tid * 16 + 4096), wg1 + ko);
        }
        __builtin_amdgcn_sched_barrier(0);   // keep stage issue ahead of compute
        bf16x8 af[4], bfr[4];
#pragma unroll
        for (int rt = 0; rt < 4; rt++)
            af[rt] = *(const bf16x8*)&Asc[swz32(wr + rt * 16 + m16, quad * 8)];
#pragma unroll
        for (int ct = 0; ct < 4; ct++)
            bfr[ct] = *(const bf16x8*)&Bsc[swz32(wc + ct * 16 + m16, quad * 8)];
#pragma unroll
        for (int rt = 0; rt < 4; rt++)
#pragma unroll
            for (int ct = 0; ct < 4; ct++)
                acc[rt][ct] = __builtin_amdgcn_mfma_f32_16x16x32_bf16(af[rt], bfr[ct], acc[rt][ct], 0, 0, 0);
        if (t < 31) __syncthreads();
    };

    for (int t = 0; t < 32; t += 2) {
        step(t,     As[0], Bs[0], As[1], Bs[1]);
        step(t + 1, As[1], Bs[1], As[0], Bs[0]);
    }

#pragma unroll
    for (int rt = 0; rt < 4; rt++)
#pragma unroll
        for (int ct = 0; ct < 4; ct++)
#pragma unroll
            for (int r = 0; r < 4; r++) {
                int row = bm + wr + rt * 16 + q4 + r;
                int col = bn + wc + ct * 16 + m16;
                u16 val = f2bf(acc[rt][ct][r] * cscale);
                if (!transV) {
                    C[(size_t)row * 1024 + col] = val;
                } else {
                    int bb = row >> 11, s = row & 2047;
                    C[((size_t)(bb * 1024 + col)) * 2048 + s] = val;
                }
            }
}

// ---- output GEMM: C(f32)[M,1024] = AO(bf16) * Wob(bf16)^T, 128x64 tile ----
__global__ __launch_bounds__(256)
void out_kernel(const u16* __restrict__ AO, const u16* __restrict__ Wob, float* __restrict__ C) {
    const int bm = blockIdx.x * 128, bn = blockIdx.y * 64;

    __shared__ u16 As[2][128 * 32];
    __shared__ u16 Bs[2][64 * 32];

    const int tid  = threadIdx.x;
    const int lane = tid & 63;
    const int w    = tid >> 6;
    const int m16  = lane & 15, quad = lane >> 4, q4 = quad * 4;
    const int c1   = tid + 256;

    const int swc = (((tid & 3) ^ ((tid >> 2) & 3)) * 8);
    const u16* ag0 = &AO[(size_t)(bm + (tid >> 2)) * 1024 + swc];
    const u16* ag1 = &AO[(size_t)(bm + (c1 >> 2)) * 1024 + swc];
    const u16* bg  = &Wob[(size_t)(bn + (tid >> 2)) * 1024 + swc];

    float4_ acc[2][4];
#pragma unroll
    for (int i = 0; i < 2; i++)
#pragma unroll
        for (int j = 0; j < 4; j++) acc[i][j] = (float4_){0.f, 0.f, 0.f, 0.f};

    async16((u16*)((char*)As[0] + (size_t)tid * 16), ag0);
    async16((u16*)((char*)As[0] + (size_t)c1 * 16), ag1);
    async16((u16*)((char*)Bs[0] + (size_t)tid * 16), bg);
    __syncthreads();

    auto step = [&](int t, const u16* Asc, const u16* Bsc, u16* Asn, u16* Bsn) {
        if (t < 31) {
            async16((u16*)((char*)Asn + (size_t)tid * 16), ag0 + (t + 1) * 32);
            async16((u16*)((char*)Asn + (size_t)c1 * 16), ag1 + (t + 1) * 32);
            async16((u16*)((char*)Bsn + (size_t)tid * 16), bg + (t + 1) * 32);
        }
        __builtin_amdgcn_sched_barrier(0);
        bf16x8 af[2], bfr[4];
#pragma unroll
        for (int rt = 0; rt < 2; rt++)
            af[rt] = *(const bf16x8*)&Asc[swz32(w * 32 + rt * 16 + m16, quad * 8)];
#pragma unroll
        for (int ct = 0; ct < 4; ct++)
            bfr[ct] = *(const bf16x8*)&Bsc[swz32(ct * 16 + m16, quad * 8)];
#pragma unroll
        for (int rt = 0; rt < 2; rt++)
#pragma unroll
            for (int ct = 0; ct < 4; ct++)
                acc[rt][ct] = __builtin_amdgcn_mfma_f32_16x16x32_bf16(af[rt], bfr[ct], acc[rt][ct], 0, 0, 0);
        if (t < 31) __syncthreads();
    };

    for (int t = 0; t < 32; t += 2) {
        step(t,     As[0], Bs[0], As[1], Bs[1]);
        step(t + 1, As[1], Bs[1], As[0], Bs[0]);
    }

#pragma unroll
    for (int rt = 0; rt < 2; rt++)
#pragma unroll
        for (int ct = 0; ct < 4; ct++)
#pragma unroll
            for (int r = 0; r < 4; r++) {
                int row = bm + w * 32 + rt * 16 + q4 + r;
                int col = bn + ct * 16 + m16;
                C[(size_t)row * 1024 + col] = acc[rt][ct][r];
            }
}

// XOR swizzle for 64-col bf16 LDS tiles.
__device__ __forceinline__ int sw64(int row, int col) {
    return row * 64 + ((((col >> 3) ^ (row & 7)) << 3) | (col & 7));
}

// Flash attention: ONE q-tile per block, 256 threads (4 waves), PAIR
// processing: K-tiles t0=2p, t1=2p+1 handled in one iteration from a
// [2][2] buffer pair. t1's QK MFMAs overlap t0's softmax VALU; t1's
// softmax overlaps t0's PV MFMAs -- two independent dep chains fill
// each other's stalls (round-13 counters: 48% idle on the serial
// QK->exp->P-LDS->PV chain). Barriers halve (1 per 2 tiles); the
// pair-p+1 stage (8 async16 at top) gets the full pair compute as
// latency cover before the bottom vmcnt(0). Stage target buf[(p+1)&1]
// was last read in pair p-1 (its barrier passed). Loop/barrier counts
// block-uniform (clamped staging). grid (16=h, 32=tq, 2=b).
__global__ __launch_bounds__(256, 2)
void attn_kernel(const u16* __restrict__ Qh, const u16* __restrict__ Kh,
                 const u16* __restrict__ Vt, u16* __restrict__ O) {
    const int h    = blockIdx.x;
    const int tq   = 31 - blockIdx.y;   // longest first
    const int b    = blockIdx.z;
    const int tid  = threadIdx.x;
    const int lane = tid & 63;
    const int w    = tid >> 6;          // 0..3
    const int m16  = lane & 15;
    const int quad = lane >> 4;
    const int q4   = quad * 4;

    __shared__ u16 Ks[2][2][64 * 64];   // [pair-parity][tile] 32 KB
    __shared__ u16 Vs[2][2][64 * 64];   // 32 KB
    __shared__ u16 Ps[2][64 * 64];      // [tile-in-pair] 16 KB

    const int srow0 = tid >> 3;                        // 0..31
    const int ssw   = (((tid & 7) ^ (srow0 & 7)) * 8); // swizzled col (u16)

    const size_t kbase = ((size_t)(b * S_)) * E_ + h * DH_;
    const size_t vbase = ((size_t)(b * 1024 + h * DH_)) * 2048;
    const u16* kg0 = &Kh[kbase + (size_t)srow0 * E_ + ssw];    // + kt*64*E_
    const u16* kg1 = kg0 + (size_t)32 * E_;
    const u16* vg0 = &Vt[vbase + (size_t)srow0 * 2048 + ssw];  // + kt*64
    const u16* vg1 = vg0 + (size_t)32 * 2048;

    bf16x8 qf[2];
    {
        const u16* qa = Qh + ((size_t)(b * S_ + tq * 64 + w * 16 + m16)) * E_ + h * DH_;
        qf[0] = ld8(qa + quad * 8);
        qf[1] = ld8(qa + 32 + quad * 8);
    }

    float l_part[4] = {0.f, 0.f, 0.f, 0.f};
    float4_ o_acc[4];
#pragma unroll
    for (int dt = 0; dt < 4; dt++) o_acc[dt] = (float4_){0.f, 0.f, 0.f, 0.f};

    auto stage_to = [&](u16* kb, u16* vb, int tile) {   // 4 async16/thread
        const size_t ko = (size_t)tile * 64 * E_;
        const int    vo = tile * 64;
        async16(kb + tid * 8, kg0 + ko);
        async16(kb + (tid + 256) * 8, kg1 + ko);
        async16(vb + tid * 8, vg0 + vo);
        async16(vb + (tid + 256) * 8, vg1 + vo);
    };
    auto stage_pair = [&](int pp, int t0) {             // 8 async16/thread
        const int ta = (t0     < tq) ? t0     : tq;     // clamp: uniform vmcnt
        const int tb = (t0 + 1 < tq) ? t0 + 1 : tq;
        stage_to(&Ks[pp][0][0], &Vs[pp][0][0], ta);
        stage_to(&Ks[pp][1][0], &Vs[pp][1][0], tb);
    };

    // QK^T of one tile into sc[4]
    auto qk = [&](const u16* Kc, float4_* sc) {
#pragma unroll
        for (int ct = 0; ct < 4; ct++) sc[ct] = (float4_){0.f, 0.f, 0.f, 0.f};
#pragma unroll
        for (int ks = 0; ks < 2; ks++)
#pragma unroll
            for (int ct = 0; ct < 4; ct++) {
                bf16x8 kf = *(const bf16x8*)&Kc[sw64(ct * 16 + m16, ks * 32 + quad * 8)];
                sc[ct] = __builtin_amdgcn_mfma_f32_16x16x32_bf16(qf[ks], kf, sc[ct], 0, 0, 0);
            }
    };
    // softmax numerator of one tile -> Pm (bf16 via v_cvt_pk pairs)
    auto sm = [&](const float4_* sc, u16* Pm, int t) {
#pragma unroll
        for (int ct = 0; ct < 4; ct++) {
            float pp[4];
            if (t != tq) {
#pragma unroll
                for (int r = 0; r < 4; r++) {
                    pp[r] = exp2f(sc[ct][r] * LOG2E_);
                    l_part[r] += pp[r];
                }
            } else {                    // diagonal tile: strict causal + (0,0)
#pragma unroll
                for (int r = 0; r < 4; r++) {
                    int i_loc = w * 16 + q4 + r;
                    int j_loc = ct * 16 + m16;
                    bool allow = (j_loc < i_loc) || (tq == 0 && i_loc == 0 && j_loc == 0);
                    pp[r] = allow ? exp2f(sc[ct][r] * LOG2E_) : 0.f;
                    l_part[r] += pp[r];
                }
            }
            union { __hip_bfloat162 h2; u16 s[2]; } u01, u23;
            u01.h2 = __float22bfloat162_rn(float2{pp[0], pp[1]});
            u23.h2 = __float22bfloat162_rn(float2{pp[2], pp[3]});
            Pm[sw64(w * 16 + q4 + 0, ct * 16 + m16)] = u01.s[0];
            Pm[sw64(w * 16 + q4 + 1, ct * 16 + m16)] = u01.s[1];
            Pm[sw64(w * 16 + q4 + 2, ct * 16 + m16)] = u23.s[0];
            Pm[sw64(w * 16 + q4 + 3, ct * 16 + m16)] = u23.s[1];
        }
    };
    // PV of one tile (accumulates o_acc)
    auto pv = [&](const u16* Pm, const u16* Vc) {
#pragma unroll
        for (int ks = 0; ks < 2; ks++) {
            bf16x8 pf = *(const bf16x8*)&Pm[sw64(w * 16 + m16, ks * 32 + quad * 8)];
#pragma unroll
            for (int dt = 0; dt < 4; dt++) {
                bf16x8 vf = *(const bf16x8*)&Vc[sw64(dt * 16 + m16, ks * 32 + quad * 8)];
                o_acc[dt] = __builtin_amdgcn_mfma_f32_16x16x32_bf16(pf, vf, o_acc[dt], 0, 0, 0);
            }
        }
    };

    // prologue: pair 0 (tiles 0,1) into parity 0
    stage_pair(0, 0);
    asm volatile("s_waitcnt vmcnt(0)" ::: "memory");
    __builtin_amdgcn_s_barrier();
    __builtin_amdgcn_sched_barrier(0);

    const int npairs = (tq + 2) >> 1;   // ceil((tq+1)/2)
    for (int p = 0; p < npairs; p++) {
        const int cur = p & 1;
        const int t0 = 2 * p, t1 = 2 * p + 1;
        const bool have1 = (t1 <= tq);  // block-uniform

        stage_pair(cur ^ 1, 2 * p + 2); // next pair; full pair-compute of cover
        __builtin_amdgcn_sched_barrier(0);

        float4_ sc0[4], sc1[4];
        qk(&Ks[cur][0][0], sc0);
        if (have1) qk(&Ks[cur][1][0], sc1);   // independent MFMA stream

        sm(sc0, &Ps[0][0], t0);
        pv(&Ps[0][0], &Vs[cur][0][0]);        // PV(t0) MFMA || SM(t1) VALU
        if (have1) {
            sm(sc1, &Ps[1][0], t1);
            pv(&Ps[1][0], &Vs[cur][1][0]);
        }

        asm volatile("s_waitcnt vmcnt(0)" ::: "memory");
        __builtin_amdgcn_s_barrier();
        __builtin_amdgcn_sched_barrier(0);
    }

    const size_t obase = ((size_t)(b * S_ + tq * 64)) * E_ + h * DH_;
#pragma unroll
    for (int r = 0; r < 4; r++) {
        float l = l_part[r];
#pragma unroll
        for (int msk = 1; msk <= 8; msk <<= 1) l += __shfl_xor(l, msk);
        float inv_l = 1.0f / l;
        int row = w * 16 + q4 + r;
#pragma unroll
        for (int dt = 0; dt < 4; dt++) {
            int col = dt * 16 + m16;
            O[obase + (size_t)row * E_ + col] = f2bf(o_acc[dt][r] * inv_l);
        }
    }
}

extern "C" void kernel_launch(void* const* d_in, const int* in_sizes, int n_in,
                              void* d_out, int out_size, void* d_ws, size_t ws_size,
                              hipStream_t stream) {
    const float* q  = (const float*)d_in[0];
    const float* k  = (const float*)d_in[1];
    const float* v  = (const float*)d_in[2];
    const float* Wq = (const float*)d_in[3];
    const float* Wk = (const float*)d_in[4];
    const float* Wv = (const float*)d_in[5];
    const float* Wo = (const float*)d_in[6];

    const size_t ME = (size_t)M_ * E_;
    u16* ws  = (u16*)d_ws;
    u16* Qh  = ws;                      // [M,E] bf16, Q pre-scaled by SCALE_
    u16* Kh  = ws + ME;
    u16* Vt  = ws + 2 * ME;             // [B][1024][2048] bf16 V^T
    u16* AO  = ws + 3 * ME;             // attn out; first 3*E2 aliased as W bufs
    u16* Wqb = AO;                      // dead before attn writes AO
    u16* Wkb = AO + E2_;
    u16* Wvb = AO + 2 * (size_t)E2_;
    u16* Wob = ws + 4 * ME;             // +2 MB
    u16* Xv  = ws + 4 * ME + E2_;       // +8 MB
    u16* Xq  = (u16*)d_out;             // d_out (16.8 MB f32) is dead until
    u16* Xk  = Xq + ME;                 // out_kernel: stash Xq,Xk there (exact fit)

    dim3 blk(256);
    conv_all_kernel<<<dim3(8192), blk, 0, stream>>>(q, k, v, Wq, Wk, Wv, Wo,
                                                    Xq, Xk, Xv, Wqb, Wkb, Wvb, Wob);
    proj_kernel<<<dim3(32, 8, 3), blk, 0, stream>>>(Xq, Xk, Xv, Wqb, Wkb, Wvb, Qh, Kh, Vt);
    attn_kernel<<<dim3(16, 32, 2), blk, 0, stream>>>(Qh, Kh, Vt, AO);
    out_kernel<<<dim3(32, 16), blk, 0, stream>>>(AO, Wob, (float*)d_out);
}